// Round 16
// baseline (383.558 us; speedup 1.0000x reference)
//
#include <hip/hip_runtime.h>

constexpr float BN_EPS = 1e-5f;

typedef __attribute__((ext_vector_type(8))) short bf16x8;
typedef __attribute__((ext_vector_type(4))) float f32x4;

__device__ __forceinline__ float4 ld4(const float* p) { return *(const float4*)p; }
__device__ __forceinline__ unsigned short f2bf(float x) {
  union { float f; unsigned u; } c; c.f = x;
  unsigned r = (c.u + 0x7fffu + ((c.u >> 16) & 1u)) >> 16;
  return (unsigned short)r;
}
__device__ __forceinline__ float bf1(unsigned short h) {
  union { unsigned i; float f; } a; a.i = ((unsigned)h) << 16; return a.f;
}
__device__ __forceinline__ float2 bf2(unsigned u) {
  union { unsigned i; float f; } lo, hi;
  lo.i = u << 16; hi.i = u & 0xffff0000u;
  return make_float2(lo.f, hi.f);
}
// packed f32->bf16 (RNE), 1 instr for 2 values
__device__ __forceinline__ unsigned pk_bf16(float lo, float hi) {
  unsigned r;
  asm("v_cvt_pk_bf16_f32 %0, %1, %2" : "=v"(r) : "v"(lo), "v"(hi));
  return r;
}

// ================= CSR build: two-level counting sort =================
__global__ __launch_bounds__(256) void csr_count_kernel(const int* __restrict__ dst, int E, int SL,
                                                        int* __restrict__ cntT) {
  __shared__ int c[256];
  c[threadIdx.x] = 0;
  __syncthreads();
  const int s = blockIdx.x;
  const int e0 = s * SL;
  const int e1 = min(E, e0 + SL);
  for (int e = e0 + threadIdx.x; e < e1; e += 256)
    atomicAdd(&c[dst[e] >> 8], 1);
  __syncthreads();
  cntT[threadIdx.x * 256 + s] = c[threadIdx.x];
}

__global__ __launch_bounds__(1024) void scan_blocks_kernel(const int* __restrict__ deg, int n,
                                                           int* __restrict__ off, int* __restrict__ bsum) {
  __shared__ int lds[1024];
  int i = blockIdx.x * 1024 + threadIdx.x;
  int v = (i < n) ? deg[i] : 0;
  lds[threadIdx.x] = v;
  __syncthreads();
  for (int s = 1; s < 1024; s <<= 1) {
    int t = (threadIdx.x >= (unsigned)s) ? lds[threadIdx.x - s] : 0;
    __syncthreads();
    lds[threadIdx.x] += t;
    __syncthreads();
  }
  if (i < n) off[i] = lds[threadIdx.x] - v;
  if (threadIdx.x == 1023) bsum[blockIdx.x] = lds[1023];
}

__global__ void scan_sums_kernel(int* __restrict__ bsum, int nb) {
  int carry = 0;
  for (int base = 0; base < nb; base += 64) {
    int l = base + (int)threadIdx.x;
    int orig = (l < nb) ? bsum[l] : 0;
    int v = orig;
    for (int s = 1; s < 64; s <<= 1) {
      int t = __shfl_up(v, s);
      if ((int)threadIdx.x >= s) v += t;
    }
    if (l < nb) bsum[l] = carry + v - orig;
    carry += __shfl(v, 63);
  }
}

__global__ __launch_bounds__(1024) void scan_add_kernel(const int* __restrict__ bsum, int n,
                                                        int* __restrict__ off, int* __restrict__ cur) {
  int i = blockIdx.x * 1024 + threadIdx.x;
  if (i < n) {
    int o = off[i] + bsum[blockIdx.x];
    off[i] = o;
    cur[i] = o;
  }
}

__global__ __launch_bounds__(256) void csr_part_kernel(const int* __restrict__ src,
                                                       const int* __restrict__ dst, int E, int SL,
                                                       const int* __restrict__ base,
                                                       unsigned* __restrict__ pairs) {
  __shared__ int curL[256];
  const int s = blockIdx.x;
  curL[threadIdx.x] = base[threadIdx.x * 256 + s];
  __syncthreads();
  const int e0 = s * SL;
  const int e1 = min(E, e0 + SL);
  for (int e = e0 + threadIdx.x; e < e1; e += 256) {
    int d = dst[e];
    int sr = src[e];
    int p = atomicAdd(&curL[d >> 8], 1);
    pairs[p] = (unsigned)sr | ((unsigned)(d & 255) << 16);
  }
}

__global__ __launch_bounds__(256) void csr_fill_kernel(const unsigned* __restrict__ pairs,
                                                       const int* __restrict__ base, int n,
                                                       int* __restrict__ deg, int* __restrict__ off,
                                                       int* __restrict__ elist) {
  __shared__ int degL[256], scanL[256], curL[256];
  const int b = blockIdx.x;
  const int p0 = base[b * 256];
  const int p1 = base[(b + 1) * 256];
  degL[threadIdx.x] = 0;
  __syncthreads();
  for (int p = p0 + threadIdx.x; p < p1; p += 256)
    atomicAdd(&degL[(pairs[p] >> 16) & 255], 1);
  __syncthreads();
  int v = degL[threadIdx.x];
  scanL[threadIdx.x] = v;
  __syncthreads();
  for (int st = 1; st < 256; st <<= 1) {
    int t = (threadIdx.x >= (unsigned)st) ? scanL[threadIdx.x - st] : 0;
    __syncthreads();
    scanL[threadIdx.x] += t;
    __syncthreads();
  }
  int excl = scanL[threadIdx.x] - v;
  curL[threadIdx.x] = excl;
  int node = b * 256 + threadIdx.x;
  if (node < n) { deg[node] = v; off[node] = p0 + excl; }
  __syncthreads();
  for (int p = p0 + threadIdx.x; p < p1; p += 256) {
    unsigned pk = pairs[p];
    int q = atomicAdd(&curL[(pk >> 16) & 255], 1);
    elist[p0 + q] = (int)(pk & 0xffffu);
  }
}

// ---------------- node projection via MFMA ----------------
// MODE 0: ob=0 -> bf16 msg SPLIT half-tables: half (col>>5) at outA + half*n*32,
//                row layout [N][32]  (each 3.2MB -> L2-resident for agg gathers)
//         ob=1 -> f32 Xr[N][64]
// MODE 1: both halves -> bf16 outA[N][128] at col ob*64+...
template <int K, bool BN, int MODE>
__global__ __launch_bounds__(256) void proj3_kernel(
    const float* __restrict__ X,
    const float* __restrict__ Wa, int lda, int koffa,
    const float* __restrict__ Wb, int ldb, int koffb,
    const float* __restrict__ scale, const float* __restrict__ shift,
    void* __restrict__ outA, void* __restrict__ outB, int n) {
  constexpr int KP = K + 4;
  __shared__ alignas(16) unsigned short ws[64 * KP];
  __shared__ alignas(16) unsigned short xs[64 * KP];
  const int ob = blockIdx.y;
  const float* W = ob ? Wb : Wa;
  const int ld = ob ? ldb : lda;
  const int koff = ob ? koffb : koffa;
  const int tid = threadIdx.x;

  for (int idx = tid; idx < 64 * K; idx += 256) {
    int o = idx / K, k = idx - o * K;
    ws[o * KP + k] = f2bf(W[o * ld + koff + k]);
  }
  const int nb = blockIdx.x * 64;
  for (int idx = tid; idx < 64 * K; idx += 256) {
    int nl = idx / K, k = idx - nl * K;
    int node = nb + nl;
    float v = (node < n) ? X[(size_t)node * K + k] : 0.f;
    if (BN) v = fmaxf(fmaf(v, scale[k], shift[k]), 0.f);
    xs[nl * KP + k] = f2bf(v);
  }
  __syncthreads();

  const int w = tid >> 6, lane = tid & 63;
  const int g = lane >> 4, c16 = lane & 15;

  f32x4 acc[4];
#pragma unroll
  for (int ct = 0; ct < 4; ++ct) acc[ct] = f32x4{0.f, 0.f, 0.f, 0.f};

  const unsigned short* xrow = &xs[(w * 16 + c16) * KP];
#pragma unroll
  for (int ks = 0; ks < K / 32; ++ks) {
    union { bf16x8 v; uint2 u[2]; } a;
    a.u[0] = *(const uint2*)(xrow + ks * 32 + g * 8);
    a.u[1] = *(const uint2*)(xrow + ks * 32 + g * 8 + 4);
#pragma unroll
    for (int ct = 0; ct < 4; ++ct) {
      union { bf16x8 v; uint2 u[2]; } b;
      const unsigned short* wrow = &ws[(ct * 16 + c16) * KP + ks * 32 + g * 8];
      b.u[0] = *(const uint2*)(wrow);
      b.u[1] = *(const uint2*)(wrow + 4);
      acc[ct] = __builtin_amdgcn_mfma_f32_16x16x32_bf16(a.v, b.v, acc[ct], 0, 0, 0);
    }
  }

#pragma unroll
  for (int ct = 0; ct < 4; ++ct) {
    int col = ct * 16 + c16;
#pragma unroll
    for (int r = 0; r < 4; ++r) {
      int node = nb + w * 16 + g * 4 + r;
      if (node < n) {
        float v = acc[ct][r];
        if (MODE == 0) {
          if (ob == 0) {
            size_t half_off = (size_t)(col >> 5) * ((size_t)n * 32);
            ((unsigned short*)outA)[half_off + (size_t)node * 32 + (col & 31)] = f2bf(v);
          } else {
            ((float*)outB)[(size_t)node * 64 + col] = v;
          }
        } else {
          ((unsigned short*)outA)[(size_t)node * 128 + ob * 64 + col] = f2bf(v);
        }
      }
    }
  }
}

// ---------------- aggregation over channel half H (L2-resident 3.2MB table) ----------
// Wave = 2 edge-parity groups x 32 channels. Each lane sums its parity's edges;
// shfl_xor(32) combines; group 0 finalizes + fused BN partial stats.
template <int H>
__global__ __launch_bounds__(256) void agg2_kernel(
    const unsigned short* __restrict__ PmH, const float* __restrict__ Xr,
    const int* __restrict__ off, const int* __restrict__ deg,
    const int* __restrict__ elist, const float* __restrict__ bl,
    float* __restrict__ HP, float* __restrict__ partials, int n) {
  int node = blockIdx.x * 4 + (threadIdx.x >> 6);
  int lane = threadIdx.x & 63;
  int c = lane & 31;
  int pe = lane >> 5;                       // edge parity group
  float hpv = 0.f;
  if (node < n) {
    int d = deg[node];
    int o = off[node];
    float a0 = 0.f, a1 = 0.f, a2 = 0.f, a3 = 0.f;
    int j = pe;
    for (; j + 6 < d; j += 8) {
      int s0 = elist[o + j], s1 = elist[o + j + 2];
      int s2 = elist[o + j + 4], s3 = elist[o + j + 6];
      a0 += bf1(PmH[(size_t)s0 * 32 + c]);
      a1 += bf1(PmH[(size_t)s1 * 32 + c]);
      a2 += bf1(PmH[(size_t)s2 * 32 + c]);
      a3 += bf1(PmH[(size_t)s3 * 32 + c]);
    }
    for (; j < d; j += 2) a0 += bf1(PmH[(size_t)elist[o + j] * 32 + c]);
    float acc = (a0 + a1) + (a2 + a3);
    acc += __shfl_xor(acc, 32);
    if (pe == 0) {
      float agg = acc / (float)(d > 0 ? d : 1);
      size_t idx = (size_t)node * 64 + H * 32 + c;
      hpv = agg + bl[H * 32 + c] + Xr[idx];
      HP[idx] = hpv;
    }
  }
  __shared__ float ls[256], lq[256];
  ls[threadIdx.x] = hpv;
  lq[threadIdx.x] = hpv * hpv;
  __syncthreads();
  if (threadIdx.x < 32) {
    float s = ls[threadIdx.x] + ls[threadIdx.x + 64] + ls[threadIdx.x + 128] + ls[threadIdx.x + 192];
    float q = lq[threadIdx.x] + lq[threadIdx.x + 64] + lq[threadIdx.x + 128] + lq[threadIdx.x + 192];
    int slot = (blockIdx.x & 31) * 128;
    atomicAdd(&partials[slot + H * 32 + threadIdx.x], s);
    atomicAdd(&partials[slot + 64 + H * 32 + threadIdx.x], q);
  }
}

__global__ void bn_finalize_kernel(const float* __restrict__ partials, int nblk, int n,
                                   const float* __restrict__ g, const float* __restrict__ be,
                                   float* __restrict__ scale, float* __restrict__ shift) {
  int c = threadIdx.x;  // 64 threads
  float s = 0.f, q = 0.f;
  for (int b = 0; b < nblk; ++b) { s += partials[b * 128 + c]; q += partials[b * 128 + 64 + c]; }
  float mean = s / (float)n;
  float var = q / (float)n - mean * mean;
  float sc = g[c] * rsqrtf(var + BN_EPS);
  scale[c] = sc;
  shift[c] = be[c] - mean * sc;
}

// ---------------- prep: pack edge-MLP weights to bf16 blob ----------------
__global__ void prep_kernel(const float* __restrict__ Wm1, const float* __restrict__ temb,
                            const float* __restrict__ bm1, const float* __restrict__ Wm2,
                            unsigned short* __restrict__ blob) {
  for (int i = threadIdx.x; i < 2048; i += 256) {
    int o = i >> 5, k = i & 31;
    float v;
    if (k < 16) {
      v = Wm1[o * 152 + 128 + k];
    } else {
      int t = k - 16;
      v = bm1[o];
#pragma unroll
      for (int q = 0; q < 8; ++q) v = fmaf(Wm1[o * 152 + 144 + q], temb[t * 8 + q], v);
    }
    blob[o * 32 + k] = f2bf(v);
  }
  for (int i = threadIdx.x; i < 2048; i += 256) {
    int j = i >> 6, k = i & 63;
    blob[2048 + j * 64 + k] = f2bf(Wm2[j * 64 + k]);
  }
}

// ---------------- fused edge MLP via MFMA (R11 config: pipelined, 1 wave) ----------------
struct RawA { uint4 r0, r1; };   // g<2: raw eattr f32x8; g>=2: r0.x = tix
struct UVfr { uint4 u0, u1, v0, v1; };

__global__ __launch_bounds__(64, 4) void edge_mfma_kernel(
    const unsigned short* __restrict__ UVb, const int* __restrict__ ei,
    const float* __restrict__ eattr, const int* __restrict__ tix,
    const unsigned short* __restrict__ blob,
    const float* __restrict__ Wm3, const float* __restrict__ bm2,
    const float* __restrict__ bm3, float* __restrict__ out, int E) {
  constexpr int P = 66;
  __shared__ unsigned short z1T[64 * P];
  unsigned* z1T32 = (unsigned*)z1T;

  const int tid = threadIdx.x;
  const int g = tid >> 4, c16 = tid & 15;
  const int base = blockIdx.x * 64;

  bf16x8 bfr[4];
#pragma unroll
  for (int ct = 0; ct < 4; ++ct)
    bfr[ct] = *(const bf16x8*)(blob + (ct * 16 + c16) * 32 + g * 8);
  bf16x8 bw[2][2];
  const unsigned short* w2b = blob + 2048;
#pragma unroll
  for (int jt = 0; jt < 2; ++jt)
#pragma unroll
    for (int ks = 0; ks < 2; ++ks)
      bw[jt][ks] = *(const bf16x8*)(w2b + (jt * 16 + c16) * 64 + ks * 32 + g * 8);
  union { bf16x8 v; short s8[8]; } bi0, bi1;
#pragma unroll
  for (int j = 0; j < 8; ++j) {
    bi0.s8[j] = (g * 8 + j == c16) ? (short)0x3F80 : (short)0;
    bi1.s8[j] = (g * 8 + j == 16 + c16) ? (short)0x3F80 : (short)0;
  }
  const float bm2c0 = bm2[c16], bm2c1 = bm2[16 + c16];
  const float2 w3c0 = make_float2(Wm3[c16], Wm3[32 + c16]);
  const float2 w3c1 = make_float2(Wm3[16 + c16], Wm3[48 + c16]);
  const float b3a = bm3[0], b3b = bm3[1];

  int sA[4], dA[4];
  bool lvA[4];
#pragma unroll
  for (int et = 0; et < 4; ++et) {
    int erow = base + et * 16 + c16;
    lvA[et] = erow < E;
    sA[et] = lvA[et] ? ei[erow] : 0;
    dA[et] = lvA[et] ? ei[E + erow] : 0;
  }

  auto load_a = [&](int et) -> RawA {
    RawA ra;
    int erow = base + et * 16 + c16;
    if (g < 2) {
      if (lvA[et]) {
        const uint4* eap = (const uint4*)(eattr + (size_t)erow * 16 + g * 8);
        ra.r0 = eap[0];
        ra.r1 = eap[1];
      } else {
        ra.r0 = make_uint4(0, 0, 0, 0);
        ra.r1 = make_uint4(0, 0, 0, 0);
      }
    } else {
      ra.r0.x = (unsigned)(lvA[et] ? tix[erow] : -1);
    }
    return ra;
  };
  auto gather_uv = [&](int et) -> UVfr {
    const uint4* ur = (const uint4*)(UVb + (size_t)sA[et] * 128);
    const uint4* vr = (const uint4*)(UVb + (size_t)dA[et] * 128);
    UVfr x;
    x.u0 = ur[g];
    x.u1 = ur[4 + g];
    x.v0 = vr[8 + g];
    x.v1 = vr[12 + g];
    return x;
  };
  auto compute = [&](int et, const RawA& ra, const UVfr& uv) {
    bf16x8 a_eaoh;
    if (g < 2) {
      union { uint4 u; float4 f; } c0, c1;
      c0.u = ra.r0; c1.u = ra.r1;
      union { bf16x8 v; unsigned u[4]; } cc;
      cc.u[0] = pk_bf16(c0.f.x, c0.f.y); cc.u[1] = pk_bf16(c0.f.z, c0.f.w);
      cc.u[2] = pk_bf16(c1.f.x, c1.f.y); cc.u[3] = pk_bf16(c1.f.z, c1.f.w);
      a_eaoh = cc.v;
    } else {
      int t = (int)ra.r0.x;
      int kb = (g - 2) * 8;
      union { bf16x8 v; short s8[8]; } cc;
#pragma unroll
      for (int j = 0; j < 8; ++j) cc.s8[j] = (t == kb + j) ? (short)0x3F80 : (short)0;
      a_eaoh = cc.v;
    }
    union { uint4 u; bf16x8 v; } au0, au1, av0, av1;
    au0.u = uv.u0; au1.u = uv.u1; av0.u = uv.v0; av1.u = uv.v1;
#pragma unroll
    for (int ct = 0; ct < 4; ++ct) {
      f32x4 acc = {0.f, 0.f, 0.f, 0.f};
      acc = __builtin_amdgcn_mfma_f32_16x16x32_bf16(a_eaoh, bfr[ct], acc, 0, 0, 0);
      const bf16x8 au = (ct < 2) ? au0.v : au1.v;
      const bf16x8 av = (ct < 2) ? av0.v : av1.v;
      const bf16x8 bi = (ct & 1) ? bi1.v : bi0.v;
      acc = __builtin_amdgcn_mfma_f32_16x16x32_bf16(au, bi, acc, 0, 0, 0);
      acc = __builtin_amdgcn_mfma_f32_16x16x32_bf16(av, bi, acc, 0, 0, 0);
      int cw = (ct * 16 + c16) * 33 + et * 8 + g * 2;
      z1T32[cw]     = pk_bf16(fmaxf(acc[0], 0.f), fmaxf(acc[1], 0.f));
      z1T32[cw + 1] = pk_bf16(fmaxf(acc[2], 0.f), fmaxf(acc[3], 0.f));
    }
  };

  RawA ra0 = load_a(0);
  UVfr uv0 = gather_uv(0);
  RawA ra1 = load_a(1);
  UVfr uv1 = gather_uv(1);
  compute(0, ra0, uv0);
  ra0 = load_a(2);
  uv0 = gather_uv(2);
  compute(1, ra1, uv1);
  ra1 = load_a(3);
  uv1 = gather_uv(3);
  compute(2, ra0, uv0);
  compute(3, ra1, uv1);
  __syncthreads();

#pragma unroll
  for (int et = 0; et < 4; ++et) {
    int ecol = et * 16 + c16;
    union { bf16x8 v; unsigned short s8[8]; } A0, A1;
#pragma unroll
    for (int j = 0; j < 8; ++j) {
      A0.s8[j] = z1T[(g * 8 + j) * P + ecol];
      A1.s8[j] = z1T[(32 + g * 8 + j) * P + ecol];
    }
    f32x4 p0 = {0.f, 0.f, 0.f, 0.f}, p1 = {0.f, 0.f, 0.f, 0.f};
#pragma unroll
    for (int jt = 0; jt < 2; ++jt) {
      float bm = jt ? bm2c1 : bm2c0;
      float2 w3 = jt ? w3c1 : w3c0;
      f32x4 acc = {bm, bm, bm, bm};
      acc = __builtin_amdgcn_mfma_f32_16x16x32_bf16(A0.v, bw[jt][0], acc, 0, 0, 0);
      acc = __builtin_amdgcn_mfma_f32_16x16x32_bf16(A1.v, bw[jt][1], acc, 0, 0, 0);
#pragma unroll
      for (int r = 0; r < 4; ++r) {
        float z = fmaxf(acc[r], 0.f);
        p0[r] = fmaf(z, w3.x, p0[r]);
        p1[r] = fmaf(z, w3.y, p1[r]);
      }
    }
#pragma unroll
    for (int m = 1; m < 16; m <<= 1) {
#pragma unroll
      for (int r = 0; r < 4; ++r) {
        p0[r] += __shfl_xor(p0[r], m, 16);
        p1[r] += __shfl_xor(p1[r], m, 16);
      }
    }
    if (c16 == 0) {
      int eo = base + et * 16 + g * 4;
      if (eo + 3 < E) {
        float4 f0 = make_float4(p0[0] + b3a, p1[0] + b3b, p0[1] + b3a, p1[1] + b3b);
        float4 f1 = make_float4(p0[2] + b3a, p1[2] + b3b, p0[3] + b3a, p1[3] + b3b);
        *(float4*)&out[(size_t)eo * 2] = f0;
        *(float4*)&out[(size_t)eo * 2 + 4] = f1;
      } else {
#pragma unroll
        for (int r = 0; r < 4; ++r) {
          if (eo + r < E) {
            out[(size_t)(eo + r) * 2] = p0[r] + b3a;
            out[(size_t)(eo + r) * 2 + 1] = p1[r] + b3b;
          }
        }
      }
    }
  }
}

// ---------------- launcher ----------------
extern "C" void kernel_launch(void* const* d_in, const int* in_sizes, int n_in,
                              void* d_out, int out_size, void* d_ws, size_t ws_size,
                              hipStream_t stream) {
  const float* x    = (const float*)d_in[0];
  const int*   ei   = (const int*)d_in[1];
  const float* ea   = (const float*)d_in[2];
  const int*   tix  = (const int*)d_in[3];
  const float* temb = (const float*)d_in[4];
  const float* W1l  = (const float*)d_in[5];
  const float* b1l  = (const float*)d_in[6];
  const float* W1r  = (const float*)d_in[7];
  const float* g1   = (const float*)d_in[8];
  const float* be1  = (const float*)d_in[9];
  const float* W2l  = (const float*)d_in[10];
  const float* b2l  = (const float*)d_in[11];
  const float* W2r  = (const float*)d_in[12];
  const float* g2   = (const float*)d_in[13];
  const float* be2  = (const float*)d_in[14];
  const float* Wm1  = (const float*)d_in[15];
  const float* bm1  = (const float*)d_in[16];
  const float* Wm2  = (const float*)d_in[17];
  const float* bm2  = (const float*)d_in[18];
  const float* Wm3  = (const float*)d_in[19];
  const float* bm3  = (const float*)d_in[20];
  float* out = (float*)d_out;

  const int N = in_sizes[0] / 128;
  const int E = in_sizes[3];

  char* w = (char*)d_ws;
  auto alloc = [&](size_t bytes) -> char* {
    char* p = w;
    w += (bytes + 255) & ~(size_t)255;
    return p;
  };
  int* deg   = (int*)alloc((size_t)N * 4);
  int* off   = (int*)alloc((size_t)(N + 1) * 4);
  int* elist = (int*)alloc((size_t)E * 4);
  unsigned short* Pm  = (unsigned short*)alloc((size_t)N * 64 * 2);   // 2 bf16 half-tables [N][32]
  float*          Xr  = (float*)alloc((size_t)N * 64 * 4);            // f32 lin_r part
  unsigned short* UVb = (unsigned short*)alloc((size_t)N * 128 * 2);  // bf16 u|v table
  float* HP       = (float*)alloc((size_t)N * 64 * 4);
  float* partials = (float*)alloc(32 * 128 * 4);
  float* sc1 = (float*)alloc(64 * 4);
  float* sh1 = (float*)alloc(64 * 4);
  float* sc2 = (float*)alloc(64 * 4);
  float* sh2 = (float*)alloc(64 * 4);
  unsigned short* blob = (unsigned short*)alloc(4096 * 2);
  int* cntT = (int*)alloc(65536 * 4);
  int* base = (int*)alloc((65536 + 256) * 4);
  int* bsum = (int*)alloc(256 * 4);
  // pairs (E*4 = 12.8MB) aliases Pm+Xr (19.2MB): dead during CSR build.
  unsigned* pairs = (unsigned*)Pm;

  const int* srcp = ei;
  const int* dstp = ei + E;

  const int SL = (E + 255) / 256;        // strip length (256 strips)
  const int NB = (N + 255) >> 8;         // buckets of 256 nodes
  int nb4 = (N + 3) / 4;
  int nb64 = (N + 63) / 64;

  unsigned short* Pm0 = Pm;                         // half 0: ch 0..31
  unsigned short* Pm1 = Pm + (size_t)N * 32;        // half 1: ch 32..63

  // ---- CSR build: count -> scan(65536) -> partition -> per-bucket fill ----
  hipLaunchKernelGGL(csr_count_kernel, dim3(256), dim3(256), 0, stream, dstp, E, SL, cntT);
  hipLaunchKernelGGL(scan_blocks_kernel, dim3(64), dim3(1024), 0, stream, cntT, 65536, base, bsum);
  hipLaunchKernelGGL(scan_sums_kernel, dim3(1), dim3(64), 0, stream, bsum, 64);
  hipLaunchKernelGGL(scan_add_kernel, dim3(64), dim3(1024), 0, stream, bsum, 65536, base, base);
  hipLaunchKernelGGL(csr_part_kernel, dim3(256), dim3(256), 0, stream, srcp, dstp, E, SL, base, pairs);
  hipLaunchKernelGGL(csr_fill_kernel, dim3(NB), dim3(256), 0, stream, pairs, base, N, deg, off, elist);

  // ---- SAGE layer 1 (stats fused into agg; channel-split gathers) ----
  hipLaunchKernelGGL((proj3_kernel<128, false, 0>), dim3(nb64, 2), dim3(256), 0, stream,
                     x, W1l, 128, 0, W1r, 128, 0, (const float*)nullptr, (const float*)nullptr,
                     (void*)Pm, (void*)Xr, N);
  hipMemsetAsync(partials, 0, 32 * 128 * 4, stream);
  hipLaunchKernelGGL((agg2_kernel<0>), dim3(nb4), dim3(256), 0, stream,
                     Pm0, Xr, off, deg, elist, b1l, HP, partials, N);
  hipLaunchKernelGGL((agg2_kernel<1>), dim3(nb4), dim3(256), 0, stream,
                     Pm1, Xr, off, deg, elist, b1l, HP, partials, N);
  hipLaunchKernelGGL(bn_finalize_kernel, dim3(1), dim3(64), 0, stream, partials, 32, N, g1, be1, sc1, sh1);

  // ---- SAGE layer 2 (BN1+relu fused into projection load) ----
  hipLaunchKernelGGL((proj3_kernel<64, true, 0>), dim3(nb64, 2), dim3(256), 0, stream,
                     HP, W2l, 64, 0, W2r, 64, 0, sc1, sh1, (void*)Pm, (void*)Xr, N);
  hipMemsetAsync(partials, 0, 32 * 128 * 4, stream);
  hipLaunchKernelGGL((agg2_kernel<0>), dim3(nb4), dim3(256), 0, stream,
                     Pm0, Xr, off, deg, elist, b2l, HP, partials, N);
  hipLaunchKernelGGL((agg2_kernel<1>), dim3(nb4), dim3(256), 0, stream,
                     Pm1, Xr, off, deg, elist, b2l, HP, partials, N);
  hipLaunchKernelGGL(bn_finalize_kernel, dim3(1), dim3(64), 0, stream, partials, 32, N, g2, be2, sc2, sh2);

  // ---- u/v node precompute + weight packing ----
  hipLaunchKernelGGL((proj3_kernel<64, true, 1>), dim3(nb64, 2), dim3(256), 0, stream,
                     HP, Wm1, 152, 0, Wm1, 152, 64, sc2, sh2, (void*)UVb, (void*)nullptr, N);
  hipLaunchKernelGGL(prep_kernel, dim3(1), dim3(256), 0, stream, Wm1, temb, bm1, Wm2, blob);

  // ---- fused edge MLP (R11 config) ----
  int ebm = (E + 63) / 64;
  hipLaunchKernelGGL(edge_mfma_kernel, dim3(ebm), dim3(64), 0, stream,
                     UVb, ei, ea, tix, blob, Wm3, bm2, bm3, out, E);
}

// Round 17
// 338.511 us; speedup vs baseline: 1.1331x; 1.1331x over previous
//
#include <hip/hip_runtime.h>

constexpr float BN_EPS = 1e-5f;

typedef __attribute__((ext_vector_type(8))) short bf16x8;
typedef __attribute__((ext_vector_type(4))) float f32x4;

__device__ __forceinline__ float4 ld4(const float* p) { return *(const float4*)p; }
__device__ __forceinline__ unsigned short f2bf(float x) {
  union { float f; unsigned u; } c; c.f = x;
  unsigned r = (c.u + 0x7fffu + ((c.u >> 16) & 1u)) >> 16;
  return (unsigned short)r;
}
__device__ __forceinline__ float bf1(unsigned short h) {
  union { unsigned i; float f; } a; a.i = ((unsigned)h) << 16; return a.f;
}
__device__ __forceinline__ float2 bf2(unsigned u) {
  union { unsigned i; float f; } lo, hi;
  lo.i = u << 16; hi.i = u & 0xffff0000u;
  return make_float2(lo.f, hi.f);
}
// packed f32->bf16 (RNE), 1 instr for 2 values
__device__ __forceinline__ unsigned pk_bf16(float lo, float hi) {
  unsigned r;
  asm("v_cvt_pk_bf16_f32 %0, %1, %2" : "=v"(r) : "v"(lo), "v"(hi));
  return r;
}

// ================= CSR build: two-level counting sort =================
__global__ __launch_bounds__(256) void csr_count_kernel(const int* __restrict__ dst, int E, int SL,
                                                        int* __restrict__ cntT) {
  __shared__ int c[256];
  c[threadIdx.x] = 0;
  __syncthreads();
  const int s = blockIdx.x;
  const int e0 = s * SL;
  const int e1 = min(E, e0 + SL);
  for (int e = e0 + threadIdx.x; e < e1; e += 256)
    atomicAdd(&c[dst[e] >> 8], 1);
  __syncthreads();
  cntT[threadIdx.x * 256 + s] = c[threadIdx.x];
}

__global__ __launch_bounds__(1024) void scan_blocks_kernel(const int* __restrict__ deg, int n,
                                                           int* __restrict__ off, int* __restrict__ bsum) {
  __shared__ int lds[1024];
  int i = blockIdx.x * 1024 + threadIdx.x;
  int v = (i < n) ? deg[i] : 0;
  lds[threadIdx.x] = v;
  __syncthreads();
  for (int s = 1; s < 1024; s <<= 1) {
    int t = (threadIdx.x >= (unsigned)s) ? lds[threadIdx.x - s] : 0;
    __syncthreads();
    lds[threadIdx.x] += t;
    __syncthreads();
  }
  if (i < n) off[i] = lds[threadIdx.x] - v;
  if (threadIdx.x == 1023) bsum[blockIdx.x] = lds[1023];
}

__global__ void scan_sums_kernel(int* __restrict__ bsum, int nb) {
  int carry = 0;
  for (int base = 0; base < nb; base += 64) {
    int l = base + (int)threadIdx.x;
    int orig = (l < nb) ? bsum[l] : 0;
    int v = orig;
    for (int s = 1; s < 64; s <<= 1) {
      int t = __shfl_up(v, s);
      if ((int)threadIdx.x >= s) v += t;
    }
    if (l < nb) bsum[l] = carry + v - orig;
    carry += __shfl(v, 63);
  }
}

__global__ __launch_bounds__(1024) void scan_add_kernel(const int* __restrict__ bsum, int n,
                                                        int* __restrict__ off, int* __restrict__ cur) {
  int i = blockIdx.x * 1024 + threadIdx.x;
  if (i < n) {
    int o = off[i] + bsum[blockIdx.x];
    off[i] = o;
    cur[i] = o;
  }
}

__global__ __launch_bounds__(256) void csr_part_kernel(const int* __restrict__ src,
                                                       const int* __restrict__ dst, int E, int SL,
                                                       const int* __restrict__ base,
                                                       unsigned* __restrict__ pairs) {
  __shared__ int curL[256];
  const int s = blockIdx.x;
  curL[threadIdx.x] = base[threadIdx.x * 256 + s];
  __syncthreads();
  const int e0 = s * SL;
  const int e1 = min(E, e0 + SL);
  for (int e = e0 + threadIdx.x; e < e1; e += 256) {
    int d = dst[e];
    int sr = src[e];
    int p = atomicAdd(&curL[d >> 8], 1);
    pairs[p] = (unsigned)sr | ((unsigned)(d & 255) << 16);
  }
}

__global__ __launch_bounds__(256) void csr_fill_kernel(const unsigned* __restrict__ pairs,
                                                       const int* __restrict__ base, int n,
                                                       int* __restrict__ deg, int* __restrict__ off,
                                                       int* __restrict__ elist) {
  __shared__ int degL[256], scanL[256], curL[256];
  const int b = blockIdx.x;
  const int p0 = base[b * 256];
  const int p1 = base[(b + 1) * 256];
  degL[threadIdx.x] = 0;
  __syncthreads();
  for (int p = p0 + threadIdx.x; p < p1; p += 256)
    atomicAdd(&degL[(pairs[p] >> 16) & 255], 1);
  __syncthreads();
  int v = degL[threadIdx.x];
  scanL[threadIdx.x] = v;
  __syncthreads();
  for (int st = 1; st < 256; st <<= 1) {
    int t = (threadIdx.x >= (unsigned)st) ? scanL[threadIdx.x - st] : 0;
    __syncthreads();
    scanL[threadIdx.x] += t;
    __syncthreads();
  }
  int excl = scanL[threadIdx.x] - v;
  curL[threadIdx.x] = excl;
  int node = b * 256 + threadIdx.x;
  if (node < n) { deg[node] = v; off[node] = p0 + excl; }
  __syncthreads();
  for (int p = p0 + threadIdx.x; p < p1; p += 256) {
    unsigned pk = pairs[p];
    int q = atomicAdd(&curL[(pk >> 16) & 255], 1);
    elist[p0 + q] = (int)(pk & 0xffffu);
  }
}

// ---------------- node projection via MFMA ----------------
template <int K, bool BN, int MODE>
__global__ __launch_bounds__(256) void proj3_kernel(
    const float* __restrict__ X,
    const float* __restrict__ Wa, int lda, int koffa,
    const float* __restrict__ Wb, int ldb, int koffb,
    const float* __restrict__ scale, const float* __restrict__ shift,
    void* __restrict__ outA, void* __restrict__ outB, int n) {
  constexpr int KP = K + 4;
  __shared__ alignas(16) unsigned short ws[64 * KP];
  __shared__ alignas(16) unsigned short xs[64 * KP];
  const int ob = blockIdx.y;
  const float* W = ob ? Wb : Wa;
  const int ld = ob ? ldb : lda;
  const int koff = ob ? koffb : koffa;
  const int tid = threadIdx.x;

  for (int idx = tid; idx < 64 * K; idx += 256) {
    int o = idx / K, k = idx - o * K;
    ws[o * KP + k] = f2bf(W[o * ld + koff + k]);
  }
  const int nb = blockIdx.x * 64;
  for (int idx = tid; idx < 64 * K; idx += 256) {
    int nl = idx / K, k = idx - nl * K;
    int node = nb + nl;
    float v = (node < n) ? X[(size_t)node * K + k] : 0.f;
    if (BN) v = fmaxf(fmaf(v, scale[k], shift[k]), 0.f);
    xs[nl * KP + k] = f2bf(v);
  }
  __syncthreads();

  const int w = tid >> 6, lane = tid & 63;
  const int g = lane >> 4, c16 = lane & 15;

  f32x4 acc[4];
#pragma unroll
  for (int ct = 0; ct < 4; ++ct) acc[ct] = f32x4{0.f, 0.f, 0.f, 0.f};

  const unsigned short* xrow = &xs[(w * 16 + c16) * KP];
#pragma unroll
  for (int ks = 0; ks < K / 32; ++ks) {
    union { bf16x8 v; uint2 u[2]; } a;
    a.u[0] = *(const uint2*)(xrow + ks * 32 + g * 8);
    a.u[1] = *(const uint2*)(xrow + ks * 32 + g * 8 + 4);
#pragma unroll
    for (int ct = 0; ct < 4; ++ct) {
      union { bf16x8 v; uint2 u[2]; } b;
      const unsigned short* wrow = &ws[(ct * 16 + c16) * KP + ks * 32 + g * 8];
      b.u[0] = *(const uint2*)(wrow);
      b.u[1] = *(const uint2*)(wrow + 4);
      acc[ct] = __builtin_amdgcn_mfma_f32_16x16x32_bf16(a.v, b.v, acc[ct], 0, 0, 0);
    }
  }

#pragma unroll
  for (int ct = 0; ct < 4; ++ct) {
    int col = ct * 16 + c16;
#pragma unroll
    for (int r = 0; r < 4; ++r) {
      int node = nb + w * 16 + g * 4 + r;
      if (node < n) {
        float v = acc[ct][r];
        if (MODE == 0) {
          if (ob == 0) ((unsigned short*)outA)[(size_t)node * 64 + col] = f2bf(v);
          else         ((float*)outB)[(size_t)node * 64 + col] = v;
        } else {
          ((unsigned short*)outA)[(size_t)node * 128 + ob * 64 + col] = f2bf(v);
        }
      }
    }
  }
}

// ---------------- aggregation (monolithic 8-wide) + fused BN stats ----------------
// partials has 32 spread slots of 128 floats: [slot][c]=sum, [slot][64+c]=sumsq.
// Must be zeroed before launch. Float atomics: ordering-nondeterministic rounding
// only (~1e-7 rel) -- within validation tolerance.
__global__ __launch_bounds__(256) void agg_kernel(
    const unsigned short* __restrict__ Pm, const float* __restrict__ Xr,
    const int* __restrict__ off, const int* __restrict__ deg,
    const int* __restrict__ elist, const float* __restrict__ bl,
    float* __restrict__ HP, float* __restrict__ partials, int n) {
  int node = blockIdx.x * 4 + (threadIdx.x >> 6);
  int c = threadIdx.x & 63;
  float hpv = 0.f;
  if (node < n) {
    int d = deg[node];
    int o = off[node];
    float a0 = 0.f, a1 = 0.f, a2 = 0.f, a3 = 0.f;
    float a4 = 0.f, a5 = 0.f, a6 = 0.f, a7 = 0.f;
    int j = 0;
    for (; j + 8 <= d; j += 8) {
      int s0 = elist[o + j + 0], s1 = elist[o + j + 1], s2 = elist[o + j + 2], s3 = elist[o + j + 3];
      int s4 = elist[o + j + 4], s5 = elist[o + j + 5], s6 = elist[o + j + 6], s7 = elist[o + j + 7];
      a0 += bf1(Pm[(size_t)s0 * 64 + c]);
      a1 += bf1(Pm[(size_t)s1 * 64 + c]);
      a2 += bf1(Pm[(size_t)s2 * 64 + c]);
      a3 += bf1(Pm[(size_t)s3 * 64 + c]);
      a4 += bf1(Pm[(size_t)s4 * 64 + c]);
      a5 += bf1(Pm[(size_t)s5 * 64 + c]);
      a6 += bf1(Pm[(size_t)s6 * 64 + c]);
      a7 += bf1(Pm[(size_t)s7 * 64 + c]);
    }
    for (; j < d; ++j) a0 += bf1(Pm[(size_t)elist[o + j] * 64 + c]);
    float acc = ((a0 + a1) + (a2 + a3)) + ((a4 + a5) + (a6 + a7));
    float agg = acc / (float)(d > 0 ? d : 1);
    size_t idx = (size_t)node * 64 + c;
    hpv = agg + bl[c] + Xr[idx];
    HP[idx] = hpv;
  }
  __shared__ float ls[256], lq[256];
  ls[threadIdx.x] = hpv;
  lq[threadIdx.x] = hpv * hpv;
  __syncthreads();
  if (threadIdx.x < 64) {
    float s = ls[threadIdx.x] + ls[threadIdx.x + 64] + ls[threadIdx.x + 128] + ls[threadIdx.x + 192];
    float q = lq[threadIdx.x] + lq[threadIdx.x + 64] + lq[threadIdx.x + 128] + lq[threadIdx.x + 192];
    int slot = (blockIdx.x & 31) * 128;
    atomicAdd(&partials[slot + c], s);
    atomicAdd(&partials[slot + 64 + c], q);
  }
}

__global__ void bn_finalize_kernel(const float* __restrict__ partials, int nblk, int n,
                                   const float* __restrict__ g, const float* __restrict__ be,
                                   float* __restrict__ scale, float* __restrict__ shift) {
  int c = threadIdx.x;  // 64 threads
  float s = 0.f, q = 0.f;
  for (int b = 0; b < nblk; ++b) { s += partials[b * 128 + c]; q += partials[b * 128 + 64 + c]; }
  float mean = s / (float)n;
  float var = q / (float)n - mean * mean;
  float sc = g[c] * rsqrtf(var + BN_EPS);
  scale[c] = sc;
  shift[c] = be[c] - mean * sc;
}

// ---------------- prep: pack edge-MLP weights to bf16 blob ----------------
__global__ void prep_kernel(const float* __restrict__ Wm1, const float* __restrict__ temb,
                            const float* __restrict__ bm1, const float* __restrict__ Wm2,
                            unsigned short* __restrict__ blob) {
  for (int i = threadIdx.x; i < 2048; i += 256) {
    int o = i >> 5, k = i & 31;
    float v;
    if (k < 16) {
      v = Wm1[o * 152 + 128 + k];
    } else {
      int t = k - 16;
      v = bm1[o];
#pragma unroll
      for (int q = 0; q < 8; ++q) v = fmaf(Wm1[o * 152 + 144 + q], temb[t * 8 + q], v);
    }
    blob[o * 32 + k] = f2bf(v);
  }
  for (int i = threadIdx.x; i < 2048; i += 256) {
    int j = i >> 6, k = i & 63;
    blob[2048 + j * 64 + k] = f2bf(Wm2[j * 64 + k]);
  }
}

// ---------------- fused edge MLP via MFMA (R11 config: pipelined, 1 wave) ----------------
struct RawA { uint4 r0, r1; };   // g<2: raw eattr f32x8; g>=2: r0.x = tix
struct UVfr { uint4 u0, u1, v0, v1; };

__global__ __launch_bounds__(64, 4) void edge_mfma_kernel(
    const unsigned short* __restrict__ UVb, const int* __restrict__ ei,
    const float* __restrict__ eattr, const int* __restrict__ tix,
    const unsigned short* __restrict__ blob,
    const float* __restrict__ Wm3, const float* __restrict__ bm2,
    const float* __restrict__ bm3, float* __restrict__ out, int E) {
  constexpr int P = 66;
  __shared__ unsigned short z1T[64 * P];
  unsigned* z1T32 = (unsigned*)z1T;

  const int tid = threadIdx.x;
  const int g = tid >> 4, c16 = tid & 15;
  const int base = blockIdx.x * 64;

  bf16x8 bfr[4];
#pragma unroll
  for (int ct = 0; ct < 4; ++ct)
    bfr[ct] = *(const bf16x8*)(blob + (ct * 16 + c16) * 32 + g * 8);
  bf16x8 bw[2][2];
  const unsigned short* w2b = blob + 2048;
#pragma unroll
  for (int jt = 0; jt < 2; ++jt)
#pragma unroll
    for (int ks = 0; ks < 2; ++ks)
      bw[jt][ks] = *(const bf16x8*)(w2b + (jt * 16 + c16) * 64 + ks * 32 + g * 8);
  union { bf16x8 v; short s8[8]; } bi0, bi1;
#pragma unroll
  for (int j = 0; j < 8; ++j) {
    bi0.s8[j] = (g * 8 + j == c16) ? (short)0x3F80 : (short)0;
    bi1.s8[j] = (g * 8 + j == 16 + c16) ? (short)0x3F80 : (short)0;
  }
  const float bm2c0 = bm2[c16], bm2c1 = bm2[16 + c16];
  const float2 w3c0 = make_float2(Wm3[c16], Wm3[32 + c16]);
  const float2 w3c1 = make_float2(Wm3[16 + c16], Wm3[48 + c16]);
  const float b3a = bm3[0], b3b = bm3[1];

  int sA[4], dA[4];
  bool lvA[4];
#pragma unroll
  for (int et = 0; et < 4; ++et) {
    int erow = base + et * 16 + c16;
    lvA[et] = erow < E;
    sA[et] = lvA[et] ? ei[erow] : 0;
    dA[et] = lvA[et] ? ei[E + erow] : 0;
  }

  auto load_a = [&](int et) -> RawA {
    RawA ra;
    int erow = base + et * 16 + c16;
    if (g < 2) {
      if (lvA[et]) {
        const uint4* eap = (const uint4*)(eattr + (size_t)erow * 16 + g * 8);
        ra.r0 = eap[0];
        ra.r1 = eap[1];
      } else {
        ra.r0 = make_uint4(0, 0, 0, 0);
        ra.r1 = make_uint4(0, 0, 0, 0);
      }
    } else {
      ra.r0.x = (unsigned)(lvA[et] ? tix[erow] : -1);
    }
    return ra;
  };
  auto gather_uv = [&](int et) -> UVfr {
    const uint4* ur = (const uint4*)(UVb + (size_t)sA[et] * 128);
    const uint4* vr = (const uint4*)(UVb + (size_t)dA[et] * 128);
    UVfr x;
    x.u0 = ur[g];
    x.u1 = ur[4 + g];
    x.v0 = vr[8 + g];
    x.v1 = vr[12 + g];
    return x;
  };
  auto compute = [&](int et, const RawA& ra, const UVfr& uv) {
    bf16x8 a_eaoh;
    if (g < 2) {
      union { uint4 u; float4 f; } c0, c1;
      c0.u = ra.r0; c1.u = ra.r1;
      union { bf16x8 v; unsigned u[4]; } cc;
      cc.u[0] = pk_bf16(c0.f.x, c0.f.y); cc.u[1] = pk_bf16(c0.f.z, c0.f.w);
      cc.u[2] = pk_bf16(c1.f.x, c1.f.y); cc.u[3] = pk_bf16(c1.f.z, c1.f.w);
      a_eaoh = cc.v;
    } else {
      int t = (int)ra.r0.x;
      int kb = (g - 2) * 8;
      union { bf16x8 v; short s8[8]; } cc;
#pragma unroll
      for (int j = 0; j < 8; ++j) cc.s8[j] = (t == kb + j) ? (short)0x3F80 : (short)0;
      a_eaoh = cc.v;
    }
    union { uint4 u; bf16x8 v; } au0, au1, av0, av1;
    au0.u = uv.u0; au1.u = uv.u1; av0.u = uv.v0; av1.u = uv.v1;
#pragma unroll
    for (int ct = 0; ct < 4; ++ct) {
      f32x4 acc = {0.f, 0.f, 0.f, 0.f};
      acc = __builtin_amdgcn_mfma_f32_16x16x32_bf16(a_eaoh, bfr[ct], acc, 0, 0, 0);
      const bf16x8 au = (ct < 2) ? au0.v : au1.v;
      const bf16x8 av = (ct < 2) ? av0.v : av1.v;
      const bf16x8 bi = (ct & 1) ? bi1.v : bi0.v;
      acc = __builtin_amdgcn_mfma_f32_16x16x32_bf16(au, bi, acc, 0, 0, 0);
      acc = __builtin_amdgcn_mfma_f32_16x16x32_bf16(av, bi, acc, 0, 0, 0);
      int cw = (ct * 16 + c16) * 33 + et * 8 + g * 2;
      z1T32[cw]     = pk_bf16(fmaxf(acc[0], 0.f), fmaxf(acc[1], 0.f));
      z1T32[cw + 1] = pk_bf16(fmaxf(acc[2], 0.f), fmaxf(acc[3], 0.f));
    }
  };

  RawA ra0 = load_a(0);
  UVfr uv0 = gather_uv(0);
  RawA ra1 = load_a(1);
  UVfr uv1 = gather_uv(1);
  compute(0, ra0, uv0);
  ra0 = load_a(2);
  uv0 = gather_uv(2);
  compute(1, ra1, uv1);
  ra1 = load_a(3);
  uv1 = gather_uv(3);
  compute(2, ra0, uv0);
  compute(3, ra1, uv1);
  __syncthreads();

#pragma unroll
  for (int et = 0; et < 4; ++et) {
    int ecol = et * 16 + c16;
    union { bf16x8 v; unsigned short s8[8]; } A0, A1;
#pragma unroll
    for (int j = 0; j < 8; ++j) {
      A0.s8[j] = z1T[(g * 8 + j) * P + ecol];
      A1.s8[j] = z1T[(32 + g * 8 + j) * P + ecol];
    }
    f32x4 p0 = {0.f, 0.f, 0.f, 0.f}, p1 = {0.f, 0.f, 0.f, 0.f};
#pragma unroll
    for (int jt = 0; jt < 2; ++jt) {
      float bm = jt ? bm2c1 : bm2c0;
      float2 w3 = jt ? w3c1 : w3c0;
      f32x4 acc = {bm, bm, bm, bm};
      acc = __builtin_amdgcn_mfma_f32_16x16x32_bf16(A0.v, bw[jt][0], acc, 0, 0, 0);
      acc = __builtin_amdgcn_mfma_f32_16x16x32_bf16(A1.v, bw[jt][1], acc, 0, 0, 0);
#pragma unroll
      for (int r = 0; r < 4; ++r) {
        float z = fmaxf(acc[r], 0.f);
        p0[r] = fmaf(z, w3.x, p0[r]);
        p1[r] = fmaf(z, w3.y, p1[r]);
      }
    }
#pragma unroll
    for (int m = 1; m < 16; m <<= 1) {
#pragma unroll
      for (int r = 0; r < 4; ++r) {
        p0[r] += __shfl_xor(p0[r], m, 16);
        p1[r] += __shfl_xor(p1[r], m, 16);
      }
    }
    if (c16 == 0) {
      int eo = base + et * 16 + g * 4;
      if (eo + 3 < E) {
        float4 f0 = make_float4(p0[0] + b3a, p1[0] + b3b, p0[1] + b3a, p1[1] + b3b);
        float4 f1 = make_float4(p0[2] + b3a, p1[2] + b3b, p0[3] + b3a, p1[3] + b3b);
        *(float4*)&out[(size_t)eo * 2] = f0;
        *(float4*)&out[(size_t)eo * 2 + 4] = f1;
      } else {
#pragma unroll
        for (int r = 0; r < 4; ++r) {
          if (eo + r < E) {
            out[(size_t)(eo + r) * 2] = p0[r] + b3a;
            out[(size_t)(eo + r) * 2 + 1] = p1[r] + b3b;
          }
        }
      }
    }
  }
}

// ---------------- launcher ----------------
extern "C" void kernel_launch(void* const* d_in, const int* in_sizes, int n_in,
                              void* d_out, int out_size, void* d_ws, size_t ws_size,
                              hipStream_t stream) {
  const float* x    = (const float*)d_in[0];
  const int*   ei   = (const int*)d_in[1];
  const float* ea   = (const float*)d_in[2];
  const int*   tix  = (const int*)d_in[3];
  const float* temb = (const float*)d_in[4];
  const float* W1l  = (const float*)d_in[5];
  const float* b1l  = (const float*)d_in[6];
  const float* W1r  = (const float*)d_in[7];
  const float* g1   = (const float*)d_in[8];
  const float* be1  = (const float*)d_in[9];
  const float* W2l  = (const float*)d_in[10];
  const float* b2l  = (const float*)d_in[11];
  const float* W2r  = (const float*)d_in[12];
  const float* g2   = (const float*)d_in[13];
  const float* be2  = (const float*)d_in[14];
  const float* Wm1  = (const float*)d_in[15];
  const float* bm1  = (const float*)d_in[16];
  const float* Wm2  = (const float*)d_in[17];
  const float* bm2  = (const float*)d_in[18];
  const float* Wm3  = (const float*)d_in[19];
  const float* bm3  = (const float*)d_in[20];
  float* out = (float*)d_out;

  const int N = in_sizes[0] / 128;
  const int E = in_sizes[3];

  char* w = (char*)d_ws;
  auto alloc = [&](size_t bytes) -> char* {
    char* p = w;
    w += (bytes + 255) & ~(size_t)255;
    return p;
  };
  int* deg   = (int*)alloc((size_t)N * 4);
  int* off   = (int*)alloc((size_t)(N + 1) * 4);
  int* elist = (int*)alloc((size_t)E * 4);
  unsigned short* Pm  = (unsigned short*)alloc((size_t)N * 64 * 2);   // bf16 msg table
  float*          Xr  = (float*)alloc((size_t)N * 64 * 4);            // f32 lin_r part
  unsigned short* UVb = (unsigned short*)alloc((size_t)N * 128 * 2);  // bf16 u|v table
  float* HP       = (float*)alloc((size_t)N * 64 * 4);
  float* partials = (float*)alloc(32 * 128 * 4);
  float* sc1 = (float*)alloc(64 * 4);
  float* sh1 = (float*)alloc(64 * 4);
  float* sc2 = (float*)alloc(64 * 4);
  float* sh2 = (float*)alloc(64 * 4);
  unsigned short* blob = (unsigned short*)alloc(4096 * 2);
  int* cntT = (int*)alloc(65536 * 4);
  int* base = (int*)alloc((65536 + 256) * 4);
  int* bsum = (int*)alloc(256 * 4);
  // pairs (E*4 = 12.8MB) aliases Pm+Xr (19.2MB): dead during CSR build.
  unsigned* pairs = (unsigned*)Pm;

  const int* srcp = ei;
  const int* dstp = ei + E;

  const int SL = (E + 255) / 256;        // strip length (256 strips)
  const int NB = (N + 255) >> 8;         // buckets of 256 nodes
  int nb4 = (N + 3) / 4;
  int nb64 = (N + 63) / 64;

  // ---- CSR build: count -> scan(65536) -> partition -> per-bucket fill ----
  hipLaunchKernelGGL(csr_count_kernel, dim3(256), dim3(256), 0, stream, dstp, E, SL, cntT);
  hipLaunchKernelGGL(scan_blocks_kernel, dim3(64), dim3(1024), 0, stream, cntT, 65536, base, bsum);
  hipLaunchKernelGGL(scan_sums_kernel, dim3(1), dim3(64), 0, stream, bsum, 64);
  hipLaunchKernelGGL(scan_add_kernel, dim3(64), dim3(1024), 0, stream, bsum, 65536, base, base);
  hipLaunchKernelGGL(csr_part_kernel, dim3(256), dim3(256), 0, stream, srcp, dstp, E, SL, base, pairs);
  hipLaunchKernelGGL(csr_fill_kernel, dim3(NB), dim3(256), 0, stream, pairs, base, N, deg, off, elist);

  // ---- SAGE layer 1 (stats fused into agg) ----
  hipLaunchKernelGGL((proj3_kernel<128, false, 0>), dim3(nb64, 2), dim3(256), 0, stream,
                     x, W1l, 128, 0, W1r, 128, 0, (const float*)nullptr, (const float*)nullptr,
                     (void*)Pm, (void*)Xr, N);
  hipMemsetAsync(partials, 0, 32 * 128 * 4, stream);
  hipLaunchKernelGGL(agg_kernel, dim3(nb4), dim3(256), 0, stream,
                     Pm, Xr, off, deg, elist, b1l, HP, partials, N);
  hipLaunchKernelGGL(bn_finalize_kernel, dim3(1), dim3(64), 0, stream, partials, 32, N, g1, be1, sc1, sh1);

  // ---- SAGE layer 2 (BN1+relu fused into projection load) ----
  hipLaunchKernelGGL((proj3_kernel<64, true, 0>), dim3(nb64, 2), dim3(256), 0, stream,
                     HP, W2l, 64, 0, W2r, 64, 0, sc1, sh1, (void*)Pm, (void*)Xr, N);
  hipMemsetAsync(partials, 0, 32 * 128 * 4, stream);
  hipLaunchKernelGGL(agg_kernel, dim3(nb4), dim3(256), 0, stream,
                     Pm, Xr, off, deg, elist, b2l, HP, partials, N);
  hipLaunchKernelGGL(bn_finalize_kernel, dim3(1), dim3(64), 0, stream, partials, 32, N, g2, be2, sc2, sh2);

  // ---- u/v node precompute + weight packing ----
  hipLaunchKernelGGL((proj3_kernel<64, true, 1>), dim3(nb64, 2), dim3(256), 0, stream,
                     HP, Wm1, 152, 0, Wm1, 152, 64, sc2, sh2, (void*)UVb, (void*)nullptr, N);
  hipLaunchKernelGGL(prep_kernel, dim3(1), dim3(256), 0, stream, Wm1, temb, bm1, Wm2, blob);

  // ---- fused edge MLP (R11 config) ----
  int ebm = (E + 63) / 64;
  hipLaunchKernelGGL(edge_mfma_kernel, dim3(ebm), dim3(64), 0, stream,
                     UVb, ei, ea, tix, blob, Wm3, bm2, bm3, out, E);
}